// Round 1
// baseline (183.390 us; speedup 1.0000x reference)
//
#include <hip/hip_runtime.h>

// x: (128, 32, 2, 64, 64) f32.  out: (128, 32) f32.
// plaq[b,h,i,j] = t0[i][j] + t1[(i+1)%64][j] - t0[i][(j+1)%64] - t1[i][j]
// out[b,h] = mean_{i,j} cos(plaq)

__global__ __launch_bounds__(256) void plaq_mean_cos_kernel(
    const float* __restrict__ x, float* __restrict__ out) {
    const int bh = blockIdx.x;                       // 0..4095  (b*32 + h)
    const float* __restrict__ base = x + (size_t)bh * 8192;  // [2][64][64]

    __shared__ float sh[8192];                       // 32 KB: t0 then t1
    const int t = threadIdx.x;

    // Stage both planes into LDS with float4 loads: 2048 float4s, 8/thread.
    {
        float4* __restrict__ sh4 = (float4*)sh;
        const float4* __restrict__ src = (const float4*)base;
        #pragma unroll
        for (int k = 0; k < 8; ++k)
            sh4[t + k * 256] = src[t + k * 256];
    }
    __syncthreads();

    const float* __restrict__ t0 = sh;
    const float* __restrict__ t1 = sh + 4096;

    float sum = 0.0f;
    #pragma unroll
    for (int k = 0; k < 16; ++k) {
        const int idx = t + k * 256;     // 0..4095
        const int i  = idx >> 6;
        const int j  = idx & 63;
        const int ip = (i + 1) & 63;
        const int jp = (j + 1) & 63;
        const float plaq = t0[idx] + t1[(ip << 6) | j]
                         - t0[(i << 6) | jp] - t1[idx];
        sum += __cosf(plaq);             // v_cos_f32; error ~1e-6 for |x|<~12
    }

    // Wave (64-lane) butterfly reduce.
    #pragma unroll
    for (int off = 32; off > 0; off >>= 1)
        sum += __shfl_down(sum, off, 64);

    __shared__ float wsum[4];
    const int lane = t & 63;
    const int wave = t >> 6;
    if (lane == 0) wsum[wave] = sum;
    __syncthreads();
    if (t == 0)
        out[bh] = (wsum[0] + wsum[1] + wsum[2] + wsum[3]) * (1.0f / 4096.0f);
}

extern "C" void kernel_launch(void* const* d_in, const int* in_sizes, int n_in,
                              void* d_out, int out_size, void* d_ws, size_t ws_size,
                              hipStream_t stream) {
    const float* x = (const float*)d_in[0];
    float* out = (float*)d_out;
    // 128*32 = 4096 (b,h) slices, one block each.
    plaq_mean_cos_kernel<<<4096, 256, 0, stream>>>(x, out);
}

// Round 2
// 182.923 us; speedup vs baseline: 1.0026x; 1.0026x over previous
//
#include <hip/hip_runtime.h>

// x: (128, 32, 2, 64, 64) f32.  out: (128, 32) f32.
// plaq[b,h,i,j] = t0[i][j] + t1[(i+1)%64][j] - t0[i][(j+1)%64] - t1[i][j]
// out[b,h] = mean_{i,j} cos(plaq)
//
// LDS-free: lane = column j (64 lanes = 64 cols), wave w owns rows
// 16w..16w+15.  t0[i][j+1] via __shfl(lane+1); t1[i+1][j] via software
// pipeline (next row's load), one extra boundary row load per wave.
// All 33 loads/lane are independent dword loads -> hoisted, deep vmcnt
// queue, no barriers, ~16 B LDS -> occupancy capped by VGPRs only.

__global__ __launch_bounds__(256) void plaq_mean_cos_kernel(
    const float* __restrict__ x, float* __restrict__ out) {
    const int t    = threadIdx.x;
    const int lane = t & 63;        // column j
    const int w    = t >> 6;        // wave 0..3: rows 16w..16w+15
    const int bh   = blockIdx.x;    // 0..4095

    const float* __restrict__ base = x + (size_t)bh * 8192;  // [2][64][64]
    const float* __restrict__ t0p  = base;                   // theta0 [64][64]
    const float* __restrict__ t1p  = base + 4096;            // theta1 [64][64]

    const int r0 = w << 4;          // first row of this wave

    float sum = 0.0f;
    float t1_cur = t1p[(r0 << 6) + lane];   // t1[16w][j]
    #pragma unroll
    for (int k = 0; k < 16; ++k) {
        const int i     = r0 + k;
        const int inext = (i + 1) & 63;     // wraps 63 -> 0
        const float t0_cur  = t0p[(i << 6) + lane];
        const float t1_next = t1p[(inext << 6) + lane];
        const float t0_rght = __shfl(t0_cur, (lane + 1) & 63, 64);
        const float plaq = t0_cur + t1_next - t0_rght - t1_cur;
        sum += __cosf(plaq);                // v_cos_f32; err ~1e-6 for |x|<~12
        t1_cur = t1_next;
    }

    // Wave (64-lane) butterfly reduce.
    #pragma unroll
    for (int off = 32; off > 0; off >>= 1)
        sum += __shfl_down(sum, off, 64);

    __shared__ float wsum[4];
    if (lane == 0) wsum[w] = sum;
    __syncthreads();
    if (t == 0)
        out[bh] = (wsum[0] + wsum[1] + wsum[2] + wsum[3]) * (1.0f / 4096.0f);
}

extern "C" void kernel_launch(void* const* d_in, const int* in_sizes, int n_in,
                              void* d_out, int out_size, void* d_ws, size_t ws_size,
                              hipStream_t stream) {
    const float* x = (const float*)d_in[0];
    float* out = (float*)d_out;
    // 128*32 = 4096 (b,h) slices, one block each.
    plaq_mean_cos_kernel<<<4096, 256, 0, stream>>>(x, out);
}

// Round 3
// 179.828 us; speedup vs baseline: 1.0198x; 1.0172x over previous
//
#include <hip/hip_runtime.h>

// x: (128, 32, 2, 64, 64) f32.  out: (128, 32) f32.
// plaq[b,h,i,j] = t0[i][j] + t1[(i+1)%64][j] - t0[i][(j+1)%64] - t1[i][j]
// out[b,h] = mean_{i,j} cos(plaq)
//
// float4 version: lane L handles row dr=L>>4 of a 4-row group, cols
// 4c..4c+3 (c=L&15).  Wave w owns rows 16w..16w+15 in 4 iterations.
// Row-neighbor t1[i+1][j] comes from a redundant float4 load at +1 row
// (same cache lines as t1[i] of this/next iter -> L1 hit, no extra HBM).
// Col-neighbor t0[i][j+1]: in-register (.y/.z/.w) except the float4
// boundary, which is one ds_bpermute of the next lane's .x.

__global__ __launch_bounds__(256) void plaq_mean_cos_kernel(
    const float* __restrict__ x, float* __restrict__ out) {
    const int t    = threadIdx.x;
    const int lane = t & 63;
    const int w    = t >> 6;            // wave: rows 16w..16w+15
    const int dr   = lane >> 4;         // row-in-group 0..3
    const int c    = lane & 15;         // col group: cols 4c..4c+3
    const int bh   = blockIdx.x;

    const float* __restrict__ base = x + (size_t)bh * 8192;  // [2][64][64]
    const float* __restrict__ t0p  = base;
    const float* __restrict__ t1p  = base + 4096;

    // lane index for the col-neighbor's .x: same dr, col group c+1 (mod 16)
    const int nlane = (lane & 48) | ((c + 1) & 15);

    float sum = 0.0f;
    #pragma unroll
    for (int k = 0; k < 4; ++k) {
        const int i   = (w << 4) + (k << 2) + dr;   // this lane's row
        const int inx = (i + 1) & 63;               // row neighbor (wraps)
        const int off = (i << 6) + (c << 2);
        const float4 t0v = *(const float4*)&t0p[off];
        const float4 t1v = *(const float4*)&t1p[off];
        const float4 t1n = *(const float4*)&t1p[(inx << 6) + (c << 2)];
        const float  nx  = __shfl(t0v.x, nlane, 64);  // t0[i][4(c+1)]

        sum += __cosf(t0v.x + t1n.x - t0v.y - t1v.x);
        sum += __cosf(t0v.y + t1n.y - t0v.z - t1v.y);
        sum += __cosf(t0v.z + t1n.z - t0v.w - t1v.z);
        sum += __cosf(t0v.w + t1n.w - nx    - t1v.w);
    }

    // Wave (64-lane) butterfly reduce.
    #pragma unroll
    for (int off = 32; off > 0; off >>= 1)
        sum += __shfl_down(sum, off, 64);

    __shared__ float wsum[4];
    if (lane == 0) wsum[w] = sum;
    __syncthreads();
    if (t == 0)
        out[bh] = (wsum[0] + wsum[1] + wsum[2] + wsum[3]) * (1.0f / 4096.0f);
}

extern "C" void kernel_launch(void* const* d_in, const int* in_sizes, int n_in,
                              void* d_out, int out_size, void* d_ws, size_t ws_size,
                              hipStream_t stream) {
    const float* x = (const float*)d_in[0];
    float* out = (float*)d_out;
    plaq_mean_cos_kernel<<<4096, 256, 0, stream>>>(x, out);
}